// Round 12
// baseline (134.435 us; speedup 1.0000x reference)
//
#include <hip/hip_runtime.h>
#include <hip/hip_fp16.h>

// DCNv2 R12: LDS-banded gather — cut L2 traffic 10x on the bilinear sample.
//   k_fused: block = 2 output rows (128 px), 512 thr / 8 waves, 1 block/CU.
//   Stage x rows [ho0-2, ho0+4] (7 rows, 114.7KB) in LDS once; all 9 taps
//   gather via conflict-free ds_read_b32 (lane = channel pair). k_params
//   packs {w00|w01, w10|w11, coords|in-band flag}; out-of-band px (rare,
//   offsets unbounded) -> wave-uniform scalar branch to global loads.
//   S single-buffered [128][68]; 2 raw barriers/tap; W frags fly over them.

typedef unsigned int u32;
typedef __attribute__((ext_vector_type(8))) _Float16 f16x8;
typedef __attribute__((ext_vector_type(4))) float f32x4;

union U16 { uint4 u; f16x8 h; };
union H2U { __half2 h2; u32 u; };

static __device__ __forceinline__ u32 pkh(float a, float b) {
    H2U c; c.h2 = __float22half2_rn(make_float2(a, b)); return c.u;
}
static __device__ __forceinline__ u32 h1(float f) {
    return (u32)__half_as_ushort(__float2half_rn(f));
}
static __device__ __forceinline__ u32 hfma2u(u32 a, u32 w, u32 acc) {
    H2U x, y, z; x.u = a; y.u = w; z.u = acc;
    z.h2 = __hfma2(x.h2, y.h2, z.h2); return z.u;
}
static __device__ __forceinline__ u32 hmul2u(u32 a, u32 w) {
    H2U x, y; x.u = a; y.u = w;
    y.h2 = __hmul2(x.h2, y.h2); return y.u;
}

#define B_   16
#define HW_  4096
#define CU_  64          // 128 ch = 64 fp16-pair words

// ---------------- kernel 1: NCHW f32 -> NHWC fp16 ----------------
__global__ __launch_bounds__(256) void k_transpose(const float* __restrict__ x,
                                                   u32* __restrict__ xtu) {
    __shared__ float tile[32][129];
    int blk = blockIdx.x, t = threadIdx.x;
    int b = blk >> 7, hw0 = (blk & 127) << 5;
    int hwl = t & 31, cg = t >> 5;
    const float* src = x + (size_t)b * 128 * HW_ + hw0 + hwl;
#pragma unroll
    for (int i = 0; i < 16; ++i) { int c = cg + (i << 3); tile[hwl][c] = src[(size_t)c * HW_]; }
    __syncthreads();
    u32* dst = xtu + ((size_t)b * HW_ + hw0) * CU_;
    int u = t & 63, hq = t >> 6;
#pragma unroll
    for (int j = 0; j < 8; ++j) {
        int hw = (hq << 3) + j;
        dst[(size_t)hw * CU_ + u] = pkh(tile[hw][2 * u], tile[hw][2 * u + 1]);
    }
}

// ---------------- kernel 2: weight prep ----------------
__global__ __launch_bounds__(256) void k_prep(const float* __restrict__ weight,
                                              const float* __restrict__ off_w,
                                              uint4* __restrict__ wtv,
                                              u32* __restrict__ woffu) {
    int idx = blockIdx.x * 256 + threadIdx.x;
    if (idx < 18432) {
        int l = idx & 63, og = (idx >> 6) & 7, ks = (idx >> 9) & 3, n = idx >> 11;
        int o = og * 16 + (l & 15);
        int c0 = ks * 32 + (l >> 4) * 8;
        u32 r[4];
#pragma unroll
        for (int q = 0; q < 4; ++q) {
            int c = c0 + 2 * q;
            r[q] = pkh(weight[((size_t)(o * 128 + c)) * 9 + n],
                       weight[((size_t)(o * 128 + c + 1)) * 9 + n]);
        }
        wtv[idx] = make_uint4(r[0], r[1], r[2], r[3]);
    } else {
        int k = idx - 18432;
        int o = k / 576, r = k % 576;
        int tap = r / 64, cu = r % 64, c = cu * 2;
        u32 v = 0u;
        if (o < 27) {
            float a = off_w[((size_t)(o * 128 + c)) * 9 + tap];
            float b = off_w[((size_t)(o * 128 + c + 1)) * 9 + tap];
            v = pkh(a, b);
        }
        woffu[k] = v;
    }
}

// ---------------- kernel 3: offset/mask conv via MFMA ----------------
__global__ __launch_bounds__(256) void k_offconv(const u32* __restrict__ xtu,
                                                 const u32* __restrict__ woffu,
                                                 const float* __restrict__ off_b,
                                                 float* __restrict__ offout) {
    __shared__ __align__(16) u32 S[3][64][64];
    int blk = ((blockIdx.x & 7) << 7) + (blockIdx.x >> 3);   // XCD-chunked
    int t = threadIdx.x;
    int b = blk >> 6, ho = blk & 63;
    const u32* xb = xtu + (size_t)b * HW_ * CU_;
    const uint4 z4 = {0u, 0u, 0u, 0u};
#pragma unroll
    for (int i = 0; i < 12; ++i) {
        int li = t + (i << 8);
        int r = li >> 10, rem = li & 1023;
        int px = rem >> 4, ch = rem & 15;
        int yy = ho + r - 1;
        uint4 v = ((unsigned)yy < 64u) ? *(const uint4*)(xb + ((yy << 6) + px) * CU_ + (ch << 2)) : z4;
        *(uint4*)&S[r][px][(ch ^ (px & 7)) << 2] = v;
    }
    __syncthreads();
    int lane = t & 63, w = t >> 6, l15 = lane & 15, lhi = lane >> 4;
    int ob = w >> 1, pb0 = (w & 1) << 1;
    f32x4 acc[2];
    acc[0] = (f32x4){0.f, 0.f, 0.f, 0.f};
    acc[1] = (f32x4){0.f, 0.f, 0.f, 0.f};
#pragma unroll 1
    for (int tap = 0; tap < 9; ++tap) {
        int ky = tap / 3, kx = tap % 3;
        int yy = ho + ky - 1;
        if ((unsigned)yy >= 64u) continue;
        U16 af[4];
#pragma unroll
        for (int ks = 0; ks < 4; ++ks)
            af[ks].u = *(const uint4*)(woffu + (size_t)(ob * 16 + l15) * 576
                                       + tap * 64 + ks * 16 + lhi * 4);
#pragma unroll
        for (int pp = 0; pp < 2; ++pp) {
            int pr = ((pb0 + pp) << 4) + l15;
            int pxs = pr + kx - 1;
            bool v = (unsigned)pxs < 64u;
            int pxc = v ? pxs : 0;
#pragma unroll
            for (int ks = 0; ks < 4; ++ks) {
                U16 sf;
                sf.u = v ? *(const uint4*)&S[ky][pxc][((ks * 4 + lhi) ^ (pxc & 7)) << 2] : z4;
                acc[pp] = __builtin_amdgcn_mfma_f32_16x16x32_f16(af[ks].h, sf.h, acc[pp], 0, 0, 0);
            }
        }
    }
    float* dst = offout + (size_t)b * 27 * HW_ + (ho << 6);
#pragma unroll
    for (int pp = 0; pp < 2; ++pp)
#pragma unroll
        for (int r = 0; r < 4; ++r) {
            int o = ob * 16 + lhi * 4 + r;
            if (o < 27) {
                float s = acc[pp][r] + off_b[o];
                if (o >= 18) s = 1.f / (1.f + __expf(-s));
                dst[(size_t)o * HW_ + ((pb0 + pp) << 4) + l15] = s;
            }
        }
}

// ---------------- kernel 3.5: pack per-sample params ----------------
// layout: params[((b*32+rp)*9 + tap)*128 + local], local = (ho&1)*64 + wo
// uint4 = {w00|w01<<16, w10|w11<<16, y0c|x0c<<6|y1c<<12|x1c<<18|inb<<24, 0}
__global__ __launch_bounds__(256) void k_params(const float* __restrict__ offout,
                                                uint4* __restrict__ params) {
    int g = blockIdx.x * 256 + threadIdx.x;    // 589824 total
    int local = g & 127;
    int tmp = g >> 7;
    int tap = tmp % 9, brp = tmp / 9;
    int rp = brp & 31, b = brp >> 5;
    int ho = (rp << 1) + (local >> 6), wo = local & 63;
    int ho0 = rp << 1;
    const float* ob_ = offout + (size_t)b * 27 * HW_ + ho * 64 + wo;
    float dy = ob_[(size_t)(2 * tap) * HW_];
    float dx = ob_[(size_t)(2 * tap + 1) * HW_];
    float m  = ob_[(size_t)(18 + tap) * HW_];
    float ys = (float)(ho + tap / 3 - 1) + dy;
    float xs = (float)(wo + tap % 3 - 1) + dx;
    float y0f = floorf(ys), x0f = floorf(xs);
    float fy = ys - y0f, fx = xs - x0f;
    int y0 = (int)y0f, x0 = (int)x0f;
    bool vy0 = (unsigned)y0 < 64u, vy1 = (unsigned)(y0 + 1) < 64u;
    bool vx0 = (unsigned)x0 < 64u, vx1 = (unsigned)(x0 + 1) < 64u;
    u32 h00 = h1((vy0 && vx0) ? (1.f - fy) * (1.f - fx) * m : 0.f);
    u32 h01 = h1((vy0 && vx1) ? (1.f - fy) * fx * m : 0.f);
    u32 h10 = h1((vy1 && vx0) ? fy * (1.f - fx) * m : 0.f);
    u32 h11 = h1((vy1 && vx1) ? fy * fx * m : 0.f);
    int y0c = min(max(y0, 0), 63), y1c = min(max(y0 + 1, 0), 63);
    int x0c = min(max(x0, 0), 63), x1c = min(max(x0 + 1, 0), 63);
    u32 inb = (y0c >= ho0 - 2 && y1c <= ho0 + 4) ? 1u : 0u;
    u32 C = (u32)y0c | ((u32)x0c << 6) | ((u32)y1c << 12) | ((u32)x1c << 18) | (inb << 24);
    params[g] = make_uint4(h00 | (h01 << 16), h10 | (h11 << 16), C, 0u);
}

// ---------------- kernel 4: fused sample + MFMA, LDS-banded gather ----------
__global__ __launch_bounds__(512, 1) void k_fused(const u32* __restrict__ xtu,
                                                  const uint4* __restrict__ wtv,
                                                  const u32* __restrict__ paramsU,
                                                  const float* __restrict__ bias,
                                                  float* __restrict__ out) {
    __shared__ __align__(16) u32 XB[7 * 4096];   // 7-row band, 114688 B
    __shared__ __align__(16) u32 S[128][68];     // 34816 B
    __shared__ __align__(16) u32 PRM[2][512];    // 4096 B
    int raw = blockIdx.x;
    int blk = ((raw & 7) << 6) + (raw >> 3);     // XCD-chunked, 512 = 8*64
    int t = threadIdx.x;
    int b = blk >> 5, rp = blk & 31, ho0 = rp << 1;
    int w = t >> 6, lane = t & 63, l15 = lane & 15, lhi = lane >> 4;
    int q = w >> 1, g = w & 1;                   // o-group (32 outs), px-group (64 px)
    int o0 = q * 32;
    int lane4 = lane << 2;

    f32x4 acc[2][4];
#pragma unroll
    for (int ob = 0; ob < 2; ++ob)
#pragma unroll
        for (int pb = 0; pb < 4; ++pb) acc[ob][pb] = (f32x4){0.f, 0.f, 0.f, 0.f};

    const u32* xb = xtu + (size_t)b * HW_ * CU_;
    const char* xbb = (const char*)xb;
    const u32* pU = paramsU + ((size_t)(b * 32 + rp) * 9) * 512 + t;

    // --- stage 7-row band (clamped) + params(tap0) ---
#pragma unroll
    for (int i = 0; i < 14; ++i) {
        int idx = t + (i << 9);                  // uint4 index, 7168 total
        int r = idx >> 10, c4 = idx & 1023;
        int phys = min(max(ho0 - 2 + r, 0), 63);
        ((uint4*)XB)[idx] = *(const uint4*)(xb + ((size_t)phys << 12) + (c4 << 2));
    }
    PRM[0][t] = pU[0];
    __syncthreads();

#pragma unroll 1
    for (int n = 0; n < 9; ++n) {
        int buf = n & 1;
        // prefetch next tap's param slice (vmem; lands before barrier1)
        u32 prn = 0u;
        if (n < 8) prn = pU[(size_t)(n + 1) * 512];
        if (n > 0) {   // protect S from previous tap's MFMA readers
            __builtin_amdgcn_sched_barrier(0);
            __builtin_amdgcn_s_barrier();
            __builtin_amdgcn_sched_barrier(0);
        }
        // --- blend own 16 px from LDS band (or rare global fallback) ---
#pragma unroll
        for (int j = 0; j < 16; ++j) {
            int p = (w << 4) + j;
            uint4 P = *(const uint4*)&PRM[buf][p << 2];
            u32 wA = P.x, wB = P.y, C = P.z;
            u32 w00p = (wA & 0xFFFFu) | (wA << 16);
            u32 w01p = (wA >> 16) | (wA & 0xFFFF0000u);
            u32 w10p = (wB & 0xFFFFu) | (wB << 16);
            u32 w11p = (wB >> 16) | (wB & 0xFFFF0000u);
            int y0c = C & 63, x0c = (C >> 6) & 63;
            int y1c = (C >> 12) & 63, x1c = (C >> 18) & 63;
            u32 v0, v1, v2, v3;
            if (__builtin_amdgcn_readfirstlane((C >> 24) & 1)) {
                int s0 = (y0c - ho0 + 2) << 12, s1 = (y1c - ho0 + 2) << 12;
                v0 = XB[s0 + (x0c << 6) + lane];
                v1 = XB[s0 + (x1c << 6) + lane];
                v2 = XB[s1 + (x0c << 6) + lane];
                v3 = XB[s1 + (x1c << 6) + lane];
            } else {
                v0 = *(const u32*)(xbb + (y0c << 14) + (x0c << 8) + lane4);
                v1 = *(const u32*)(xbb + (y0c << 14) + (x1c << 8) + lane4);
                v2 = *(const u32*)(xbb + (y1c << 14) + (x0c << 8) + lane4);
                v3 = *(const u32*)(xbb + (y1c << 14) + (x1c << 8) + lane4);
            }
            u32 r = hfma2u(v3, w11p, hfma2u(v2, w10p,
                    hfma2u(v1, w01p, hmul2u(v0, w00p))));
            S[p][lane] = r;
        }
        // --- W fragments (vmem, fly across barrier1) ---
        U16 wf[2][4];
#pragma unroll
        for (int ob = 0; ob < 2; ++ob)
#pragma unroll
            for (int ks = 0; ks < 4; ++ks)
                wf[ob][ks].u = wtv[(((n << 2) + ks) * 8 + (q << 1) + ob) * 64 + lane];
        // --- write next tap's params, then barrier1 (LDS drained, vmem flies) ---
        if (n < 8) PRM[buf ^ 1][t] = prn;
        asm volatile("s_waitcnt lgkmcnt(0)" ::: "memory");
        __builtin_amdgcn_sched_barrier(0);
        __builtin_amdgcn_s_barrier();
        __builtin_amdgcn_sched_barrier(0);
        // --- MFMA(n): D[o][px] += W_tap * S_tap^T ---
#pragma unroll
        for (int ks = 0; ks < 4; ++ks) {
            U16 sf[4];
#pragma unroll
            for (int pb = 0; pb < 4; ++pb)
                sf[pb].u = *(const uint4*)&S[(g << 6) + pb * 16 + l15][(ks * 4 + lhi) << 2];
#pragma unroll
            for (int ob = 0; ob < 2; ++ob)
#pragma unroll
                for (int pb = 0; pb < 4; ++pb)
                    acc[ob][pb] = __builtin_amdgcn_mfma_f32_16x16x32_f16(
                        wf[ob][ks].h, sf[pb].h, acc[ob][pb], 0, 0, 0);
        }
    }
    // --- epilogue: o = o0+ob*16+lhi*4+r, row ho0+g, col pb*16+l15 ---
    float* ob_base = out + (size_t)b * 128 * HW_ + (ho0 + g) * 64;
#pragma unroll
    for (int ob = 0; ob < 2; ++ob)
#pragma unroll
        for (int r = 0; r < 4; ++r) {
            int o = o0 + ob * 16 + lhi * 4 + r;
            float bv = bias[o];
#pragma unroll
            for (int pb = 0; pb < 4; ++pb)
                ob_base[(size_t)o * HW_ + pb * 16 + l15] = acc[ob][pb][r] + bv;
        }
}

extern "C" void kernel_launch(void* const* d_in, const int* in_sizes, int n_in,
                              void* d_out, int out_size, void* d_ws, size_t ws_size,
                              hipStream_t stream) {
    const float* x      = (const float*)d_in[0];
    const float* weight = (const float*)d_in[1];
    const float* bias   = (const float*)d_in[2];
    const float* off_w  = (const float*)d_in[3];
    const float* off_b  = (const float*)d_in[4];
    float* out = (float*)d_out;

    // ws (u32 units): xtu 4194304 | offout 1769472 | wtv 294912 | woffu 18432
    //                 | params 2359296
    u32*   xtu    = (u32*)d_ws;
    float* offout = (float*)(xtu + (size_t)B_ * HW_ * CU_);
    uint4* wtv    = (uint4*)(offout + (size_t)B_ * 27 * HW_);
    u32*   woffu  = (u32*)wtv + 294912;
    uint4* params = (uint4*)(woffu + 18432);

    hipLaunchKernelGGL(k_transpose, dim3(2048), dim3(256), 0, stream, x, xtu);
    hipLaunchKernelGGL(k_prep, dim3(144), dim3(256), 0, stream, weight, off_w, wtv, woffu);
    hipLaunchKernelGGL(k_offconv, dim3(1024), dim3(256), 0, stream, xtu, woffu, off_b, offout);
    hipLaunchKernelGGL(k_params, dim3(2304), dim3(256), 0, stream, offout, params);
    hipLaunchKernelGGL(k_fused, dim3(512), dim3(512), 0, stream, xtu, wtv, (const u32*)params, bias, out);
}

// Round 13
// 120.657 us; speedup vs baseline: 1.1142x; 1.1142x over previous
//
#include <hip/hip_runtime.h>
#include <hip/hip_fp16.h>

// DCNv2 R13: 8 narrow waves per 64-px row block (2x chain concurrency vs R9,
//   same traffic). Wave w: samples 8 px (coalesced broadcast gather, validated
//   R5/R9 path), computes 16 outputs (o0 = w*16) over all 64 px.
//   Per tap: 8 uniform param loads, 32 gather loads, 8 packed blends, 4 W-frag
//   loads (wtv has 8 o-slots = one per wave), 1 syncthreads, 16 MFMA.
//   S dbuf [2][64][68] = 34.8 KB -> 4 blocks/CU; target 24+ waves/CU.

typedef unsigned int u32;
typedef __attribute__((ext_vector_type(8))) _Float16 f16x8;
typedef __attribute__((ext_vector_type(4))) float f32x4;

union U16 { uint4 u; f16x8 h; };
union H2U { __half2 h2; u32 u; };

static __device__ __forceinline__ u32 pkh(float a, float b) {
    H2U c; c.h2 = __float22half2_rn(make_float2(a, b)); return c.u;
}
static __device__ __forceinline__ u32 pkw(float w) {
    __half h = __float2half_rn(w);
    H2U c; c.h2 = __half2(h, h); return c.u;
}
static __device__ __forceinline__ u32 hfma2u(u32 a, u32 w, u32 acc) {
    H2U x, y, z; x.u = a; y.u = w; z.u = acc;
    z.h2 = __hfma2(x.h2, y.h2, z.h2); return z.u;
}
static __device__ __forceinline__ u32 hmul2u(u32 a, u32 w) {
    H2U x, y; x.u = a; y.u = w;
    y.h2 = __hmul2(x.h2, y.h2); return y.u;
}

#define B_   16
#define HW_  4096
#define CU_  64          // 128 ch = 64 fp16-pair words

// ---------------- kernel 1: NCHW f32 -> NHWC fp16 ----------------
__global__ __launch_bounds__(256) void k_transpose(const float* __restrict__ x,
                                                   u32* __restrict__ xtu) {
    __shared__ float tile[32][129];
    int blk = blockIdx.x, t = threadIdx.x;
    int b = blk >> 7, hw0 = (blk & 127) << 5;
    int hwl = t & 31, cg = t >> 5;
    const float* src = x + (size_t)b * 128 * HW_ + hw0 + hwl;
#pragma unroll
    for (int i = 0; i < 16; ++i) { int c = cg + (i << 3); tile[hwl][c] = src[(size_t)c * HW_]; }
    __syncthreads();
    u32* dst = xtu + ((size_t)b * HW_ + hw0) * CU_;
    int u = t & 63, hq = t >> 6;
#pragma unroll
    for (int j = 0; j < 8; ++j) {
        int hw = (hq << 3) + j;
        dst[(size_t)hw * CU_ + u] = pkh(tile[hw][2 * u], tile[hw][2 * u + 1]);
    }
}

// ---------------- kernel 2: weight prep ----------------
__global__ __launch_bounds__(256) void k_prep(const float* __restrict__ weight,
                                              const float* __restrict__ off_w,
                                              uint4* __restrict__ wtv,
                                              u32* __restrict__ woffu) {
    int idx = blockIdx.x * 256 + threadIdx.x;
    if (idx < 18432) {
        int l = idx & 63, og = (idx >> 6) & 7, ks = (idx >> 9) & 3, n = idx >> 11;
        int o = og * 16 + (l & 15);
        int c0 = ks * 32 + (l >> 4) * 8;
        u32 r[4];
#pragma unroll
        for (int q = 0; q < 4; ++q) {
            int c = c0 + 2 * q;
            r[q] = pkh(weight[((size_t)(o * 128 + c)) * 9 + n],
                       weight[((size_t)(o * 128 + c + 1)) * 9 + n]);
        }
        wtv[idx] = make_uint4(r[0], r[1], r[2], r[3]);
    } else {
        int k = idx - 18432;
        int o = k / 576, r = k % 576;
        int tap = r / 64, cu = r % 64, c = cu * 2;
        u32 v = 0u;
        if (o < 27) {
            float a = off_w[((size_t)(o * 128 + c)) * 9 + tap];
            float b = off_w[((size_t)(o * 128 + c + 1)) * 9 + tap];
            v = pkh(a, b);
        }
        woffu[k] = v;
    }
}

// ---------------- kernel 3: offset/mask conv via MFMA ----------------
__global__ __launch_bounds__(256) void k_offconv(const u32* __restrict__ xtu,
                                                 const u32* __restrict__ woffu,
                                                 const float* __restrict__ off_b,
                                                 float* __restrict__ offout) {
    __shared__ __align__(16) u32 S[3][64][64];
    int blk = ((blockIdx.x & 7) << 7) + (blockIdx.x >> 3);   // XCD-chunked
    int t = threadIdx.x;
    int b = blk >> 6, ho = blk & 63;
    const u32* xb = xtu + (size_t)b * HW_ * CU_;
    const uint4 z4 = {0u, 0u, 0u, 0u};
#pragma unroll
    for (int i = 0; i < 12; ++i) {
        int li = t + (i << 8);
        int r = li >> 10, rem = li & 1023;
        int px = rem >> 4, ch = rem & 15;
        int yy = ho + r - 1;
        uint4 v = ((unsigned)yy < 64u) ? *(const uint4*)(xb + ((yy << 6) + px) * CU_ + (ch << 2)) : z4;
        *(uint4*)&S[r][px][(ch ^ (px & 7)) << 2] = v;
    }
    __syncthreads();
    int lane = t & 63, w = t >> 6, l15 = lane & 15, lhi = lane >> 4;
    int ob = w >> 1, pb0 = (w & 1) << 1;
    f32x4 acc[2];
    acc[0] = (f32x4){0.f, 0.f, 0.f, 0.f};
    acc[1] = (f32x4){0.f, 0.f, 0.f, 0.f};
#pragma unroll 1
    for (int tap = 0; tap < 9; ++tap) {
        int ky = tap / 3, kx = tap % 3;
        int yy = ho + ky - 1;
        if ((unsigned)yy >= 64u) continue;
        U16 af[4];
#pragma unroll
        for (int ks = 0; ks < 4; ++ks)
            af[ks].u = *(const uint4*)(woffu + (size_t)(ob * 16 + l15) * 576
                                       + tap * 64 + ks * 16 + lhi * 4);
#pragma unroll
        for (int pp = 0; pp < 2; ++pp) {
            int pr = ((pb0 + pp) << 4) + l15;
            int pxs = pr + kx - 1;
            bool v = (unsigned)pxs < 64u;
            int pxc = v ? pxs : 0;
#pragma unroll
            for (int ks = 0; ks < 4; ++ks) {
                U16 sf;
                sf.u = v ? *(const uint4*)&S[ky][pxc][((ks * 4 + lhi) ^ (pxc & 7)) << 2] : z4;
                acc[pp] = __builtin_amdgcn_mfma_f32_16x16x32_f16(af[ks].h, sf.h, acc[pp], 0, 0, 0);
            }
        }
    }
    float* dst = offout + (size_t)b * 27 * HW_ + (ho << 6);
#pragma unroll
    for (int pp = 0; pp < 2; ++pp)
#pragma unroll
        for (int r = 0; r < 4; ++r) {
            int o = ob * 16 + lhi * 4 + r;
            if (o < 27) {
                float s = acc[pp][r] + off_b[o];
                if (o >= 18) s = 1.f / (1.f + __expf(-s));
                dst[(size_t)o * HW_ + ((pb0 + pp) << 4) + l15] = s;
            }
        }
}

// ---------------- kernel 3.5: pack per-sample params ----------------
__global__ __launch_bounds__(256) void k_params(const float* __restrict__ offout,
                                                uint4* __restrict__ paramsW,
                                                uint2* __restrict__ paramsA) {
    int g = blockIdx.x * 256 + threadIdx.x;    // 589824 total
    int wo = g & 63, r = g >> 6;
    int tap = r % 9, bho = r / 9;
    int ho = bho & 63, b = bho >> 6;
    const float* ob_ = offout + (size_t)b * 27 * HW_ + ho * 64 + wo;
    float dy = ob_[(size_t)(2 * tap) * HW_];
    float dx = ob_[(size_t)(2 * tap + 1) * HW_];
    float m  = ob_[(size_t)(18 + tap) * HW_];
    float ys = (float)(ho + tap / 3 - 1) + dy;
    float xs = (float)(wo + tap % 3 - 1) + dx;
    float y0f = floorf(ys), x0f = floorf(xs);
    float fy = ys - y0f, fx = xs - x0f;
    int y0 = (int)y0f, x0 = (int)x0f;
    bool vy0 = (unsigned)y0 < 64u, vy1 = (unsigned)(y0 + 1) < 64u;
    bool vx0 = (unsigned)x0 < 64u, vx1 = (unsigned)(x0 + 1) < 64u;
    u32 w00 = pkw((vy0 && vx0) ? (1.f - fy) * (1.f - fx) * m : 0.f);
    u32 w01 = pkw((vy0 && vx1) ? (1.f - fy) * fx * m : 0.f);
    u32 w10 = pkw((vy1 && vx0) ? fy * (1.f - fx) * m : 0.f);
    u32 w11 = pkw((vy1 && vx1) ? fy * fx * m : 0.f);
    int y0c = min(max(y0, 0), 63), y1c = min(max(y0 + 1, 0), 63);
    int x0c = min(max(x0, 0), 63), x1c = min(max(x0 + 1, 0), 63);
    u32 a00 = ((u32)y0c << 14) + ((u32)x0c << 8);   // byte addrs within batch slice
    u32 a11 = ((u32)y1c << 14) + ((u32)x1c << 8);
    paramsW[g] = make_uint4(w00, w01, w10, w11);
    paramsA[g] = make_uint2(a00, a11);
}

// ---------------- kernel 4: fused sample + MFMA, 8 narrow waves ----------------
__global__ __launch_bounds__(512, 3) void k_fused(const u32* __restrict__ xtu,
                                                  const uint4* __restrict__ wtv,
                                                  const uint4* __restrict__ paramsW,
                                                  const uint2* __restrict__ paramsA,
                                                  const float* __restrict__ bias,
                                                  float* __restrict__ out) {
    __shared__ __align__(16) u32 S[2][64][68];   // dbuf, 34.8 KB
    int blk = ((blockIdx.x & 7) << 7) + (blockIdx.x >> 3);   // XCD-chunked
    int t = threadIdx.x;
    int b = blk >> 6, ho = blk & 63;
    int w = t >> 6, lane = t & 63, l15 = lane & 15, lhi = lane >> 4;
    int o0 = w << 4;                 // 16 outputs per wave
    int lane4 = lane << 2;

    f32x4 acc[4];
#pragma unroll
    for (int pb = 0; pb < 4; ++pb) acc[pb] = (f32x4){0.f, 0.f, 0.f, 0.f};

    const char* xbb = (const char*)(xtu + (size_t)b * HW_ * CU_);
    int pbase = ((b << 6) + ho) * 9;
    const uint4* pWb = paramsW + (size_t)pbase * 64 + (w << 3);
    const uint2* pAb = paramsA + (size_t)pbase * 64 + (w << 3);

#pragma unroll 1
    for (int n = 0; n < 9; ++n) {
        const uint4* pW = pWb + n * 64;
        const uint2* pA = pAb + n * 64;
        int buf = n & 1;
        // --- gather: this wave's 8 px (wave-uniform addrs, coalesced loads) ---
        u32 ld[8][4];
#pragma unroll
        for (int j = 0; j < 8; ++j) {
            uint2 aa = pA[j];                   // wave-uniform 8B load
            u32 a00 = aa.x, a11 = aa.y;
            u32 a01 = (a00 & ~0x3FFFu) | (a11 & 0x3FFFu);
            u32 a10 = (a11 & ~0x3FFFu) | (a00 & 0x3FFFu);
            ld[j][0] = *(const u32*)(xbb + a00 + lane4);
            ld[j][1] = *(const u32*)(xbb + a01 + lane4);
            ld[j][2] = *(const u32*)(xbb + a10 + lane4);
            ld[j][3] = *(const u32*)(xbb + a11 + lane4);
        }
        // --- blend + write S ---
#pragma unroll
        for (int j = 0; j < 8; ++j) {
            uint4 ww = pW[j];                   // wave-uniform 16B load
            u32 r = hfma2u(ld[j][3], ww.w, hfma2u(ld[j][2], ww.z,
                    hfma2u(ld[j][1], ww.y, hmul2u(ld[j][0], ww.x))));
            S[buf][(w << 3) + j][lane] = r;
        }
        // --- W fragments: one o-slot per wave (coalesced 1KB loads) ---
        U16 wf[4];
#pragma unroll
        for (int ks = 0; ks < 4; ++ks)
            wf[ks].u = wtv[(((n << 2) + ks) * 8 + w) * 64 + lane];
        __syncthreads();
        // --- MFMA: D[o0..o0+16][px] += W_tap * S_tap^T ---
#pragma unroll
        for (int ks = 0; ks < 4; ++ks) {
            U16 sf[4];
#pragma unroll
            for (int pb = 0; pb < 4; ++pb)
                sf[pb].u = *(const uint4*)&S[buf][pb * 16 + l15][(ks * 4 + lhi) << 2];
#pragma unroll
            for (int pb = 0; pb < 4; ++pb)
                acc[pb] = __builtin_amdgcn_mfma_f32_16x16x32_f16(
                    wf[ks].h, sf[pb].h, acc[pb], 0, 0, 0);
        }
    }
    // --- epilogue: o = o0+lhi*4+r, px = pb*16+l15 ---
    float* ob_base = out + (size_t)b * 128 * HW_ + ho * 64;
#pragma unroll
    for (int r = 0; r < 4; ++r) {
        int o = o0 + lhi * 4 + r;
        float bv = bias[o];
#pragma unroll
        for (int pb = 0; pb < 4; ++pb)
            ob_base[(size_t)o * HW_ + pb * 16 + l15] = acc[pb][r] + bv;
    }
}

extern "C" void kernel_launch(void* const* d_in, const int* in_sizes, int n_in,
                              void* d_out, int out_size, void* d_ws, size_t ws_size,
                              hipStream_t stream) {
    const float* x      = (const float*)d_in[0];
    const float* weight = (const float*)d_in[1];
    const float* bias   = (const float*)d_in[2];
    const float* off_w  = (const float*)d_in[3];
    const float* off_b  = (const float*)d_in[4];
    float* out = (float*)d_out;

    // ws (u32 units): xtu 4194304 | offout 1769472 | wtv 73728*4 | woffu 18432
    //                 | paramsW 2359296 | paramsA 1179648
    u32*   xtu     = (u32*)d_ws;
    float* offout  = (float*)(xtu + (size_t)B_ * HW_ * CU_);
    uint4* wtv     = (uint4*)(offout + (size_t)B_ * 27 * HW_);
    u32*   woffu   = (u32*)wtv + 73728;
    uint4* paramsW = (uint4*)(woffu + 18432);
    uint2* paramsA = (uint2*)((u32*)paramsW + 2359296);

    hipLaunchKernelGGL(k_transpose, dim3(2048), dim3(256), 0, stream, x, xtu);
    hipLaunchKernelGGL(k_prep, dim3(144), dim3(256), 0, stream, weight, off_w, wtv, woffu);
    hipLaunchKernelGGL(k_offconv, dim3(1024), dim3(256), 0, stream, xtu, woffu, off_b, offout);
    hipLaunchKernelGGL(k_params, dim3(2304), dim3(256), 0, stream, offout, paramsW, paramsA);
    hipLaunchKernelGGL(k_fused, dim3(1024), dim3(512), 0, stream, xtu, wtv, paramsW, paramsA, bias, out);
}

// Round 14
// 107.586 us; speedup vs baseline: 1.2496x; 1.1215x over previous
//
#include <hip/hip_runtime.h>
#include <hip/hip_fp16.h>

// DCNv2 R14: forced-deep gather pipeline.
//   k_fused: 8 narrow waves (R13 partition: wave = 8 px sample, 16 outs MFMA).
//   Cross-tap gather: G(n+1) issued after blend(n), consumed at blend(n+1) —
//   32 ld regs live across raw s_barrier (lgkm-only; vmem stays in flight).
//   Params: single uint4/px {w00|w01, w10|w11, a0|a1<<12} staged through a
//   wave-private LDS strip (load early, ds_write late). W(n) issued before
//   G(n+1) so MFMA's in-order vmcnt wait never drains the gather queue.

typedef unsigned int u32;
typedef __attribute__((ext_vector_type(8))) _Float16 f16x8;
typedef __attribute__((ext_vector_type(4))) float f32x4;

union U16 { uint4 u; f16x8 h; };
union H2U { __half2 h2; u32 u; };

static __device__ __forceinline__ u32 pkh(float a, float b) {
    H2U c; c.h2 = __float22half2_rn(make_float2(a, b)); return c.u;
}
static __device__ __forceinline__ u32 h1(float f) {
    return (u32)__half_as_ushort(__float2half_rn(f));
}
static __device__ __forceinline__ u32 hfma2u(u32 a, u32 w, u32 acc) {
    H2U x, y, z; x.u = a; y.u = w; z.u = acc;
    z.h2 = __hfma2(x.h2, y.h2, z.h2); return z.u;
}
static __device__ __forceinline__ u32 hmul2u(u32 a, u32 w) {
    H2U x, y; x.u = a; y.u = w;
    y.h2 = __hmul2(x.h2, y.h2); return y.u;
}

#define B_   16
#define HW_  4096
#define CU_  64          // 128 ch = 64 fp16-pair words

// ---------------- kernel 1: NCHW f32 -> NHWC fp16 ----------------
__global__ __launch_bounds__(256) void k_transpose(const float* __restrict__ x,
                                                   u32* __restrict__ xtu) {
    __shared__ float tile[32][129];
    int blk = blockIdx.x, t = threadIdx.x;
    int b = blk >> 7, hw0 = (blk & 127) << 5;
    int hwl = t & 31, cg = t >> 5;
    const float* src = x + (size_t)b * 128 * HW_ + hw0 + hwl;
#pragma unroll
    for (int i = 0; i < 16; ++i) { int c = cg + (i << 3); tile[hwl][c] = src[(size_t)c * HW_]; }
    __syncthreads();
    u32* dst = xtu + ((size_t)b * HW_ + hw0) * CU_;
    int u = t & 63, hq = t >> 6;
#pragma unroll
    for (int j = 0; j < 8; ++j) {
        int hw = (hq << 3) + j;
        dst[(size_t)hw * CU_ + u] = pkh(tile[hw][2 * u], tile[hw][2 * u + 1]);
    }
}

// ---------------- kernel 2: weight prep ----------------
__global__ __launch_bounds__(256) void k_prep(const float* __restrict__ weight,
                                              const float* __restrict__ off_w,
                                              uint4* __restrict__ wtv,
                                              u32* __restrict__ woffu) {
    int idx = blockIdx.x * 256 + threadIdx.x;
    if (idx < 18432) {
        int l = idx & 63, og = (idx >> 6) & 7, ks = (idx >> 9) & 3, n = idx >> 11;
        int o = og * 16 + (l & 15);
        int c0 = ks * 32 + (l >> 4) * 8;
        u32 r[4];
#pragma unroll
        for (int q = 0; q < 4; ++q) {
            int c = c0 + 2 * q;
            r[q] = pkh(weight[((size_t)(o * 128 + c)) * 9 + n],
                       weight[((size_t)(o * 128 + c + 1)) * 9 + n]);
        }
        wtv[idx] = make_uint4(r[0], r[1], r[2], r[3]);
    } else {
        int k = idx - 18432;
        int o = k / 576, r = k % 576;
        int tap = r / 64, cu = r % 64, c = cu * 2;
        u32 v = 0u;
        if (o < 27) {
            float a = off_w[((size_t)(o * 128 + c)) * 9 + tap];
            float b = off_w[((size_t)(o * 128 + c + 1)) * 9 + tap];
            v = pkh(a, b);
        }
        woffu[k] = v;
    }
}

// ---------------- kernel 3: offset/mask conv via MFMA ----------------
__global__ __launch_bounds__(256) void k_offconv(const u32* __restrict__ xtu,
                                                 const u32* __restrict__ woffu,
                                                 const float* __restrict__ off_b,
                                                 float* __restrict__ offout) {
    __shared__ __align__(16) u32 S[3][64][64];
    int blk = ((blockIdx.x & 7) << 7) + (blockIdx.x >> 3);   // XCD-chunked
    int t = threadIdx.x;
    int b = blk >> 6, ho = blk & 63;
    const u32* xb = xtu + (size_t)b * HW_ * CU_;
    const uint4 z4 = {0u, 0u, 0u, 0u};
#pragma unroll
    for (int i = 0; i < 12; ++i) {
        int li = t + (i << 8);
        int r = li >> 10, rem = li & 1023;
        int px = rem >> 4, ch = rem & 15;
        int yy = ho + r - 1;
        uint4 v = ((unsigned)yy < 64u) ? *(const uint4*)(xb + ((yy << 6) + px) * CU_ + (ch << 2)) : z4;
        *(uint4*)&S[r][px][(ch ^ (px & 7)) << 2] = v;
    }
    __syncthreads();
    int lane = t & 63, w = t >> 6, l15 = lane & 15, lhi = lane >> 4;
    int ob = w >> 1, pb0 = (w & 1) << 1;
    f32x4 acc[2];
    acc[0] = (f32x4){0.f, 0.f, 0.f, 0.f};
    acc[1] = (f32x4){0.f, 0.f, 0.f, 0.f};
#pragma unroll 1
    for (int tap = 0; tap < 9; ++tap) {
        int ky = tap / 3, kx = tap % 3;
        int yy = ho + ky - 1;
        if ((unsigned)yy >= 64u) continue;
        U16 af[4];
#pragma unroll
        for (int ks = 0; ks < 4; ++ks)
            af[ks].u = *(const uint4*)(woffu + (size_t)(ob * 16 + l15) * 576
                                       + tap * 64 + ks * 16 + lhi * 4);
#pragma unroll
        for (int pp = 0; pp < 2; ++pp) {
            int pr = ((pb0 + pp) << 4) + l15;
            int pxs = pr + kx - 1;
            bool v = (unsigned)pxs < 64u;
            int pxc = v ? pxs : 0;
#pragma unroll
            for (int ks = 0; ks < 4; ++ks) {
                U16 sf;
                sf.u = v ? *(const uint4*)&S[ky][pxc][((ks * 4 + lhi) ^ (pxc & 7)) << 2] : z4;
                acc[pp] = __builtin_amdgcn_mfma_f32_16x16x32_f16(af[ks].h, sf.h, acc[pp], 0, 0, 0);
            }
        }
    }
    float* dst = offout + (size_t)b * 27 * HW_ + (ho << 6);
#pragma unroll
    for (int pp = 0; pp < 2; ++pp)
#pragma unroll
        for (int r = 0; r < 4; ++r) {
            int o = ob * 16 + lhi * 4 + r;
            if (o < 27) {
                float s = acc[pp][r] + off_b[o];
                if (o >= 18) s = 1.f / (1.f + __expf(-s));
                dst[(size_t)o * HW_ + ((pb0 + pp) << 4) + l15] = s;
            }
        }
}

// ---------------- kernel 3.5: pack per-sample params ----------------
// paramsP layout: [(((b*64+ho)*9+tap)*256 + (wo>>3)*32 + (wo&7)*4 + word]
// uint4 = {h00|h01<<16, h10|h11<<16, a0|a1<<12 (12-bit px addrs), 0}
__global__ __launch_bounds__(256) void k_params(const float* __restrict__ offout,
                                                uint4* __restrict__ paramsP) {
    int g = blockIdx.x * 256 + threadIdx.x;    // 589824 total
    int wo = g & 63, r = g >> 6;
    int tap = r % 9, bho = r / 9;
    int ho = bho & 63, b = bho >> 6;
    const float* ob_ = offout + (size_t)b * 27 * HW_ + ho * 64 + wo;
    float dy = ob_[(size_t)(2 * tap) * HW_];
    float dx = ob_[(size_t)(2 * tap + 1) * HW_];
    float m  = ob_[(size_t)(18 + tap) * HW_];
    float ys = (float)(ho + tap / 3 - 1) + dy;
    float xs = (float)(wo + tap % 3 - 1) + dx;
    float y0f = floorf(ys), x0f = floorf(xs);
    float fy = ys - y0f, fx = xs - x0f;
    int y0 = (int)y0f, x0 = (int)x0f;
    bool vy0 = (unsigned)y0 < 64u, vy1 = (unsigned)(y0 + 1) < 64u;
    bool vx0 = (unsigned)x0 < 64u, vx1 = (unsigned)(x0 + 1) < 64u;
    u32 h00 = h1((vy0 && vx0) ? (1.f - fy) * (1.f - fx) * m : 0.f);
    u32 h01 = h1((vy0 && vx1) ? (1.f - fy) * fx * m : 0.f);
    u32 h10 = h1((vy1 && vx0) ? fy * (1.f - fx) * m : 0.f);
    u32 h11 = h1((vy1 && vx1) ? fy * fx * m : 0.f);
    int y0c = min(max(y0, 0), 63), y1c = min(max(y0 + 1, 0), 63);
    int x0c = min(max(x0, 0), 63), x1c = min(max(x0 + 1, 0), 63);
    u32 a0 = ((u32)y0c << 6) | (u32)x0c;
    u32 a1 = ((u32)y1c << 6) | (u32)x1c;
    u32 idx4 = ((((u32)(b << 6) + ho) * 9 + tap) * 256 + ((wo >> 3) << 5) + ((wo & 7) << 2)) >> 2;
    paramsP[idx4] = make_uint4(h00 | (h01 << 16), h10 | (h11 << 16), a0 | (a1 << 12), 0u);
}

// ---------------- kernel 4: fused sample + MFMA, forced-deep pipeline ----------
__global__ __launch_bounds__(512, 4) void k_fused(const u32* __restrict__ xtu,
                                                  const uint4* __restrict__ wtv,
                                                  const u32* __restrict__ paramsP,
                                                  const float* __restrict__ bias,
                                                  float* __restrict__ out) {
    __shared__ __align__(16) u32 S[2][64][68];    // dbuf, 34.8 KB
    __shared__ __align__(16) u32 PRM[8][2][32];   // wave-private param strips, 2 KB
    int blk = ((blockIdx.x & 7) << 7) + (blockIdx.x >> 3);   // XCD-chunked
    int t = threadIdx.x;
    int b = blk >> 6, ho = blk & 63;
    int w = t >> 6, lane = t & 63, l15 = lane & 15, lhi = lane >> 4;
    int o0 = w << 4;
    int lane4 = lane << 2;
    int l31 = lane & 31;

    f32x4 acc[4];
#pragma unroll
    for (int pb = 0; pb < 4; ++pb) acc[pb] = (f32x4){0.f, 0.f, 0.f, 0.f};

    const char* xbb = (const char*)(xtu + (size_t)b * HW_ * CU_);
    const u32* pP = paramsP + (size_t)(((b << 6) + ho) * 9) * 256 + (w << 5) + l31;

    u32 ld[8][4];

#define ISSUE_G(NB)                                                          \
    _Pragma("unroll") for (int j = 0; j < 8; ++j) {                          \
        u32 w2 = PRM[w][NB][(j << 2) + 2];                                   \
        u32 a0 = (w2 & 0xFFFu) << 8;                                         \
        u32 a1 = ((w2 >> 12) & 0xFFFu) << 8;                                 \
        u32 a01 = (a0 & ~0x3FFFu) | (a1 & 0x3FFFu);                          \
        u32 a10 = (a1 & ~0x3FFFu) | (a0 & 0x3FFFu);                          \
        ld[j][0] = *(const u32*)(xbb + a0 + lane4);                          \
        ld[j][1] = *(const u32*)(xbb + a01 + lane4);                         \
        ld[j][2] = *(const u32*)(xbb + a10 + lane4);                         \
        ld[j][3] = *(const u32*)(xbb + a1 + lane4);                          \
    }

    // --- prologue: stage params(0); issue G(0); prefetch params(1) ---
    PRM[w][0][l31] = pP[0];
    __builtin_amdgcn_sched_barrier(0);
    ISSUE_G(0);
    u32 prNext = pP[256];

#pragma unroll 1
    for (int n = 0; n < 9; ++n) {
        int buf = n & 1;
        // --- W(n) fragments FIRST (in-order vmcnt: MFMA's wait won't drain G) ---
        U16 wf[4];
#pragma unroll
        for (int ks = 0; ks < 4; ++ks)
            wf[ks].u = wtv[(((n << 2) + ks) * 8 + w) * 64 + lane];
        __builtin_amdgcn_sched_barrier(0);
        // --- blend(n): weights from PRM[w][buf], data from ld (G(n)) ---
#pragma unroll
        for (int j = 0; j < 8; ++j) {
            uint4 P = *(const uint4*)&PRM[w][buf][j << 2];
            u32 w00p = (P.x & 0xFFFFu) | (P.x << 16);
            u32 w01p = (P.x >> 16) | (P.x & 0xFFFF0000u);
            u32 w10p = (P.y & 0xFFFFu) | (P.y << 16);
            u32 w11p = (P.y >> 16) | (P.y & 0xFFFF0000u);
            u32 r = hfma2u(ld[j][3], w11p, hfma2u(ld[j][2], w10p,
                    hfma2u(ld[j][1], w01p, hmul2u(ld[j][0], w00p))));
            S[buf][(w << 3) + j][lane] = r;
        }
        // --- stage params(n+1) into strip; prefetch params(n+2) ---
        if (n < 8) PRM[w][buf ^ 1][l31] = prNext;
        if (n < 7) prNext = pP[(size_t)(n + 2) * 256];
        // --- issue G(n+1): stays in flight across the barrier ---
        if (n < 8) { ISSUE_G(buf ^ 1); }
        // --- raw barrier: LDS drained, vmem NOT drained ---
        asm volatile("s_waitcnt lgkmcnt(0)" ::: "memory");
        __builtin_amdgcn_sched_barrier(0);
        __builtin_amdgcn_s_barrier();
        __builtin_amdgcn_sched_barrier(0);
        // --- MFMA(n): D[o0..o0+16][px] += W_tap * S_tap^T ---
#pragma unroll
        for (int ks = 0; ks < 4; ++ks) {
            U16 sf[4];
#pragma unroll
            for (int pb = 0; pb < 4; ++pb)
                sf[pb].u = *(const uint4*)&S[buf][pb * 16 + l15][(ks * 4 + lhi) << 2];
#pragma unroll
            for (int pb = 0; pb < 4; ++pb)
                acc[pb] = __builtin_amdgcn_mfma_f32_16x16x32_f16(
                    wf[ks].h, sf[pb].h, acc[pb], 0, 0, 0);
        }
    }
#undef ISSUE_G
    // --- epilogue: o = o0+lhi*4+r, px = pb*16+l15 ---
    float* ob_base = out + (size_t)b * 128 * HW_ + ho * 64;
#pragma unroll
    for (int r = 0; r < 4; ++r) {
        int o = o0 + lhi * 4 + r;
        float bv = bias[o];
#pragma unroll
        for (int pb = 0; pb < 4; ++pb)
            ob_base[(size_t)o * HW_ + pb * 16 + l15] = acc[pb][r] + bv;
    }
}

extern "C" void kernel_launch(void* const* d_in, const int* in_sizes, int n_in,
                              void* d_out, int out_size, void* d_ws, size_t ws_size,
                              hipStream_t stream) {
    const float* x      = (const float*)d_in[0];
    const float* weight = (const float*)d_in[1];
    const float* bias   = (const float*)d_in[2];
    const float* off_w  = (const float*)d_in[3];
    const float* off_b  = (const float*)d_in[4];
    float* out = (float*)d_out;

    // ws (u32 units): xtu 4194304 | offout 1769472 | wtv 73728 (uint4) | woffu 18432
    //                 | paramsP 2359296
    u32*   xtu     = (u32*)d_ws;
    float* offout  = (float*)(xtu + (size_t)B_ * HW_ * CU_);
    uint4* wtv     = (uint4*)(offout + (size_t)B_ * 27 * HW_);
    u32*   woffu   = (u32*)wtv + 73728;
    uint4* paramsP = (uint4*)(woffu + 18432);

    hipLaunchKernelGGL(k_transpose, dim3(2048), dim3(256), 0, stream, x, xtu);
    hipLaunchKernelGGL(k_prep, dim3(144), dim3(256), 0, stream, weight, off_w, wtv, woffu);
    hipLaunchKernelGGL(k_offconv, dim3(1024), dim3(256), 0, stream, xtu, woffu, off_b, offout);
    hipLaunchKernelGGL(k_params, dim3(2304), dim3(256), 0, stream, offout, paramsP);
    hipLaunchKernelGGL(k_fused, dim3(1024), dim3(512), 0, stream, xtu, wtv,
                       (const u32*)paramsP, bias, out);
}

// Round 15
// 92.304 us; speedup vs baseline: 1.4564x; 1.1656x over previous
//
#include <hip/hip_runtime.h>
#include <hip/hip_fp16.h>

// DCNv2 R15: R14 pipeline + pre-expanded param weights + params fused into offconv.
//   params layout: [bho][tap][wave][64 words]: words 4j..4j+3 = duplicated-pair
//   fp16 weights (w00,w01,w10,w11) for px j of the wave; word 32+j = a0|a1<<12.
//   k_offconv epilogue: acc -> OFF LDS (27x65) -> barrier -> compute params
//   in-block (no offout, no k_params kernel).
//   k_fused: identical R14 forced-deep pipeline; blend feeds v_pk_fma_f16
//   straight from the PRM uint4 (no weight re-expansion).

typedef unsigned int u32;
typedef __attribute__((ext_vector_type(8))) _Float16 f16x8;
typedef __attribute__((ext_vector_type(4))) float f32x4;

union U16 { uint4 u; f16x8 h; };
union H2U { __half2 h2; u32 u; };

static __device__ __forceinline__ u32 pkh(float a, float b) {
    H2U c; c.h2 = __float22half2_rn(make_float2(a, b)); return c.u;
}
static __device__ __forceinline__ u32 pkw(float w) {
    __half h = __float2half_rn(w);
    H2U c; c.h2 = __half2(h, h); return c.u;
}
static __device__ __forceinline__ u32 hfma2u(u32 a, u32 w, u32 acc) {
    H2U x, y, z; x.u = a; y.u = w; z.u = acc;
    z.h2 = __hfma2(x.h2, y.h2, z.h2); return z.u;
}
static __device__ __forceinline__ u32 hmul2u(u32 a, u32 w) {
    H2U x, y; x.u = a; y.u = w;
    y.h2 = __hmul2(x.h2, y.h2); return y.u;
}

#define B_   16
#define HW_  4096
#define CU_  64          // 128 ch = 64 fp16-pair words

// ---------------- kernel 1: NCHW f32 -> NHWC fp16 ----------------
__global__ __launch_bounds__(256) void k_transpose(const float* __restrict__ x,
                                                   u32* __restrict__ xtu) {
    __shared__ float tile[32][129];
    int blk = blockIdx.x, t = threadIdx.x;
    int b = blk >> 7, hw0 = (blk & 127) << 5;
    int hwl = t & 31, cg = t >> 5;
    const float* src = x + (size_t)b * 128 * HW_ + hw0 + hwl;
#pragma unroll
    for (int i = 0; i < 16; ++i) { int c = cg + (i << 3); tile[hwl][c] = src[(size_t)c * HW_]; }
    __syncthreads();
    u32* dst = xtu + ((size_t)b * HW_ + hw0) * CU_;
    int u = t & 63, hq = t >> 6;
#pragma unroll
    for (int j = 0; j < 8; ++j) {
        int hw = (hq << 3) + j;
        dst[(size_t)hw * CU_ + u] = pkh(tile[hw][2 * u], tile[hw][2 * u + 1]);
    }
}

// ---------------- kernel 2: weight prep ----------------
__global__ __launch_bounds__(256) void k_prep(const float* __restrict__ weight,
                                              const float* __restrict__ off_w,
                                              uint4* __restrict__ wtv,
                                              u32* __restrict__ woffu) {
    int idx = blockIdx.x * 256 + threadIdx.x;
    if (idx < 18432) {
        int l = idx & 63, og = (idx >> 6) & 7, ks = (idx >> 9) & 3, n = idx >> 11;
        int o = og * 16 + (l & 15);
        int c0 = ks * 32 + (l >> 4) * 8;
        u32 r[4];
#pragma unroll
        for (int q = 0; q < 4; ++q) {
            int c = c0 + 2 * q;
            r[q] = pkh(weight[((size_t)(o * 128 + c)) * 9 + n],
                       weight[((size_t)(o * 128 + c + 1)) * 9 + n]);
        }
        wtv[idx] = make_uint4(r[0], r[1], r[2], r[3]);
    } else {
        int k = idx - 18432;
        int o = k / 576, r = k % 576;
        int tap = r / 64, cu = r % 64, c = cu * 2;
        u32 v = 0u;
        if (o < 27) {
            float a = off_w[((size_t)(o * 128 + c)) * 9 + tap];
            float b = off_w[((size_t)(o * 128 + c + 1)) * 9 + tap];
            v = pkh(a, b);
        }
        woffu[k] = v;
    }
}

// ---------------- kernel 3: offset/mask conv + params (fused) ----------------
__global__ __launch_bounds__(256) void k_offconv(const u32* __restrict__ xtu,
                                                 const u32* __restrict__ woffu,
                                                 const float* __restrict__ off_b,
                                                 u32* __restrict__ params) {
    __shared__ __align__(16) u32 S[3][64][64];
    __shared__ float OFF[27][65];
    int blk = ((blockIdx.x & 7) << 7) + (blockIdx.x >> 3);   // XCD-chunked
    int t = threadIdx.x;
    int b = blk >> 6, ho = blk & 63;
    const u32* xb = xtu + (size_t)b * HW_ * CU_;
    const uint4 z4 = {0u, 0u, 0u, 0u};
#pragma unroll
    for (int i = 0; i < 12; ++i) {
        int li = t + (i << 8);
        int r = li >> 10, rem = li & 1023;
        int px = rem >> 4, ch = rem & 15;
        int yy = ho + r - 1;
        uint4 v = ((unsigned)yy < 64u) ? *(const uint4*)(xb + ((yy << 6) + px) * CU_ + (ch << 2)) : z4;
        *(uint4*)&S[r][px][(ch ^ (px & 7)) << 2] = v;
    }
    __syncthreads();
    int lane = t & 63, w = t >> 6, l15 = lane & 15, lhi = lane >> 4;
    int ob = w >> 1, pb0 = (w & 1) << 1;
    f32x4 acc[2];
    acc[0] = (f32x4){0.f, 0.f, 0.f, 0.f};
    acc[1] = (f32x4){0.f, 0.f, 0.f, 0.f};
#pragma unroll 1
    for (int tap = 0; tap < 9; ++tap) {
        int ky = tap / 3, kx = tap % 3;
        int yy = ho + ky - 1;
        if ((unsigned)yy >= 64u) continue;
        U16 af[4];
#pragma unroll
        for (int ks = 0; ks < 4; ++ks)
            af[ks].u = *(const uint4*)(woffu + (size_t)(ob * 16 + l15) * 576
                                       + tap * 64 + ks * 16 + lhi * 4);
#pragma unroll
        for (int pp = 0; pp < 2; ++pp) {
            int pr = ((pb0 + pp) << 4) + l15;
            int pxs = pr + kx - 1;
            bool v = (unsigned)pxs < 64u;
            int pxc = v ? pxs : 0;
#pragma unroll
            for (int ks = 0; ks < 4; ++ks) {
                U16 sf;
                sf.u = v ? *(const uint4*)&S[ky][pxc][((ks * 4 + lhi) ^ (pxc & 7)) << 2] : z4;
                acc[pp] = __builtin_amdgcn_mfma_f32_16x16x32_f16(af[ks].h, sf.h, acc[pp], 0, 0, 0);
            }
        }
    }
    // --- epilogue A: offsets/mask -> OFF LDS ---
#pragma unroll
    for (int pp = 0; pp < 2; ++pp)
#pragma unroll
        for (int r = 0; r < 4; ++r) {
            int o = ob * 16 + lhi * 4 + r;
            if (o < 27) {
                float s = acc[pp][r] + off_b[o];
                if (o >= 18) s = 1.f / (1.f + __expf(-s));
                OFF[o][((pb0 + pp) << 4) + l15] = s;
            }
        }
    __syncthreads();
    // --- epilogue B: compute params for this (b,ho): 9 taps x 64 px ---
    u32* pbase = params + ((size_t)((b << 6) + ho) * 9) * 512;
#pragma unroll 1
    for (int it = 0; it < 3; ++it) {
        int item = it * 256 + t;
        if (item < 576) {
            int tap = item >> 6, px = item & 63;
            float dy = OFF[2 * tap][px];
            float dx = OFF[2 * tap + 1][px];
            float m  = OFF[18 + tap][px];
            float ys = (float)(ho + tap / 3 - 1) + dy;
            float xs = (float)(px + tap % 3 - 1) + dx;
            float y0f = floorf(ys), x0f = floorf(xs);
            float fy = ys - y0f, fx = xs - x0f;
            int y0 = (int)y0f, x0 = (int)x0f;
            bool vy0 = (unsigned)y0 < 64u, vy1 = (unsigned)(y0 + 1) < 64u;
            bool vx0 = (unsigned)x0 < 64u, vx1 = (unsigned)(x0 + 1) < 64u;
            u32 w00p = pkw((vy0 && vx0) ? (1.f - fy) * (1.f - fx) * m : 0.f);
            u32 w01p = pkw((vy0 && vx1) ? (1.f - fy) * fx * m : 0.f);
            u32 w10p = pkw((vy1 && vx0) ? fy * (1.f - fx) * m : 0.f);
            u32 w11p = pkw((vy1 && vx1) ? fy * fx * m : 0.f);
            int y0c = min(max(y0, 0), 63), y1c = min(max(y0 + 1, 0), 63);
            int x0c = min(max(x0, 0), 63), x1c = min(max(x0 + 1, 0), 63);
            u32 a0 = ((u32)y0c << 6) | (u32)x0c;
            u32 a1 = ((u32)y1c << 6) | (u32)x1c;
            u32* dst = pbase + (size_t)tap * 512 + ((px >> 3) << 6);
            *(uint4*)&dst[(px & 7) << 2] = make_uint4(w00p, w01p, w10p, w11p);
            dst[32 + (px & 7)] = a0 | (a1 << 12);
        }
    }
}

// ---------------- kernel 4: fused sample + MFMA, forced-deep pipeline ----------
__global__ __launch_bounds__(512, 4) void k_fused(const u32* __restrict__ xtu,
                                                  const uint4* __restrict__ wtv,
                                                  const u32* __restrict__ params,
                                                  const float* __restrict__ bias,
                                                  float* __restrict__ out) {
    __shared__ __align__(16) u32 S[2][64][68];    // dbuf, 34.8 KB
    __shared__ __align__(16) u32 PRM[8][2][64];   // wave-private param strips, 4 KB
    int blk = ((blockIdx.x & 7) << 7) + (blockIdx.x >> 3);   // XCD-chunked
    int t = threadIdx.x;
    int b = blk >> 6, ho = blk & 63;
    int w = t >> 6, lane = t & 63, l15 = lane & 15, lhi = lane >> 4;
    int o0 = w << 4;
    int lane4 = lane << 2;

    f32x4 acc[4];
#pragma unroll
    for (int pb = 0; pb < 4; ++pb) acc[pb] = (f32x4){0.f, 0.f, 0.f, 0.f};

    const char* xbb = (const char*)(xtu + (size_t)b * HW_ * CU_);
    const u32* pP = params + (size_t)(((b << 6) + ho) * 9) * 512 + (w << 6) + lane;

    u32 ld[8][4];

#define ISSUE_G(NB)                                                          \
    _Pragma("unroll") for (int j = 0; j < 8; ++j) {                          \
        u32 A = PRM[w][NB][32 + j];                                          \
        u32 a0 = (A & 0xFFFu) << 8;                                          \
        u32 a1 = ((A >> 12) & 0xFFFu) << 8;                                  \
        u32 a01 = (a0 & ~0x3FFFu) | (a1 & 0x3FFFu);                          \
        u32 a10 = (a1 & ~0x3FFFu) | (a0 & 0x3FFFu);                          \
        ld[j][0] = *(const u32*)(xbb + a0 + lane4);                          \
        ld[j][1] = *(const u32*)(xbb + a01 + lane4);                         \
        ld[j][2] = *(const u32*)(xbb + a10 + lane4);                         \
        ld[j][3] = *(const u32*)(xbb + a1 + lane4);                          \
    }

    // --- prologue: stage params(0); issue G(0); prefetch params(1) ---
    PRM[w][0][lane] = pP[0];
    __builtin_amdgcn_sched_barrier(0);
    ISSUE_G(0);
    u32 prNext = pP[512];

#pragma unroll 1
    for (int n = 0; n < 9; ++n) {
        int buf = n & 1;
        // --- W(n) fragments FIRST (in-order vmcnt: MFMA's wait won't drain G) ---
        U16 wf[4];
#pragma unroll
        for (int ks = 0; ks < 4; ++ks)
            wf[ks].u = wtv[(((n << 2) + ks) * 8 + w) * 64 + lane];
        __builtin_amdgcn_sched_barrier(0);
        // --- blend(n): pre-expanded weights straight from PRM ---
#pragma unroll
        for (int j = 0; j < 8; ++j) {
            uint4 ww = *(const uint4*)&PRM[w][buf][j << 2];
            u32 r = hfma2u(ld[j][3], ww.w, hfma2u(ld[j][2], ww.z,
                    hfma2u(ld[j][1], ww.y, hmul2u(ld[j][0], ww.x))));
            S[buf][(w << 3) + j][lane] = r;
        }
        // --- stage params(n+1); prefetch params(n+2) ---
        if (n < 8) PRM[w][buf ^ 1][lane] = prNext;
        if (n < 7) prNext = pP[(size_t)(n + 2) * 512];
        // --- issue G(n+1): stays in flight across the barrier ---
        if (n < 8) { ISSUE_G(buf ^ 1); }
        // --- raw barrier: LDS drained, vmem NOT drained ---
        asm volatile("s_waitcnt lgkmcnt(0)" ::: "memory");
        __builtin_amdgcn_sched_barrier(0);
        __builtin_amdgcn_s_barrier();
        __builtin_amdgcn_sched_barrier(0);
        // --- MFMA(n): D[o0..o0+16][px] += W_tap * S_tap^T ---
#pragma unroll
        for (int ks = 0; ks < 4; ++ks) {
            U16 sf[4];
#pragma unroll
            for (int pb = 0; pb < 4; ++pb)
                sf[pb].u = *(const uint4*)&S[buf][pb * 16 + l15][(ks * 4 + lhi) << 2];
#pragma unroll
            for (int pb = 0; pb < 4; ++pb)
                acc[pb] = __builtin_amdgcn_mfma_f32_16x16x32_f16(
                    wf[ks].h, sf[pb].h, acc[pb], 0, 0, 0);
        }
    }
#undef ISSUE_G
    // --- epilogue: o = o0+lhi*4+r, px = pb*16+l15 ---
    float* ob_base = out + (size_t)b * 128 * HW_ + ho * 64;
#pragma unroll
    for (int r = 0; r < 4; ++r) {
        int o = o0 + lhi * 4 + r;
        float bv = bias[o];
#pragma unroll
        for (int pb = 0; pb < 4; ++pb)
            ob_base[(size_t)o * HW_ + pb * 16 + l15] = acc[pb][r] + bv;
    }
}

extern "C" void kernel_launch(void* const* d_in, const int* in_sizes, int n_in,
                              void* d_out, int out_size, void* d_ws, size_t ws_size,
                              hipStream_t stream) {
    const float* x      = (const float*)d_in[0];
    const float* weight = (const float*)d_in[1];
    const float* bias   = (const float*)d_in[2];
    const float* off_w  = (const float*)d_in[3];
    const float* off_b  = (const float*)d_in[4];
    float* out = (float*)d_out;

    // ws (u32 units): xtu 4194304 | wtv 73728 (uint4 = 294912 B) | woffu 18432
    //                 | params 4718592   -> ~35.3 MB
    u32*   xtu    = (u32*)d_ws;
    uint4* wtv    = (uint4*)(xtu + (size_t)B_ * HW_ * CU_);
    u32*   woffu  = (u32*)wtv + 73728;
    u32*   params = woffu + 18432;

    hipLaunchKernelGGL(k_transpose, dim3(2048), dim3(256), 0, stream, x, xtu);
    hipLaunchKernelGGL(k_prep, dim3(144), dim3(256), 0, stream, weight, off_w, wtv, woffu);
    hipLaunchKernelGGL(k_offconv, dim3(1024), dim3(256), 0, stream, xtu, woffu, off_b, params);
    hipLaunchKernelGGL(k_fused, dim3(1024), dim3(512), 0, stream, xtu, wtv, params, bias, out);
}